// Round 5
// baseline (300.259 us; speedup 1.0000x reference)
//
#include <hip/hip_runtime.h>
#include <math.h>

// ---------------------------------------------------------------------------
// InteractionBlock: gather -> per-edge tensor-product -> scatter -> linear
// N=50000 nodes, E=800000 edges, MUL=32.
//
// Round-5:
//  * sv1 stored as bf16x4 (ushort4, 8 B/lane): random gather demand halved
//    (410 -> 205 MB), dwordx2 loads. bf16 only on the gathered operand.
//  * phase-2: straight-line 2-way unroll (2 outstanding gathers/group),
//    NO per-iteration conditional prefetch (round-4 regression reverted).
//  * everything else from round 4 kept (k-major rec, packed SV, staged
//    node_final, folded hist).
//
// ws layout (4B units):
//   sv1[N*64 (as ushort N*128)] | SV[N*256] | cnt[N] | rs[N] |
//   bsum[64] | boff[64] | perm[E]        (~67.6 MB)
// ---------------------------------------------------------------------------

__device__ __forceinline__ unsigned short f2bf(float x) {
    unsigned u = __float_as_uint(x);
    u += 0x7FFFu + ((u >> 16) & 1u);   // RNE
    return (unsigned short)(u >> 16);
}
__device__ __forceinline__ float bf2f(unsigned short h) {
    return __uint_as_float(((unsigned)h) << 16);
}

__global__ __launch_bounds__(256) void node_prep(
    const float* __restrict__ nf, const float* __restrict__ W1_s,
    const float* __restrict__ W1_v, const int* __restrict__ eidx,
    int* __restrict__ cnt, ushort* __restrict__ sv1, int N, int E)
{
    __shared__ float w1s[1024];
    __shared__ float w1v[1024];
    __shared__ float nrow[8][128];

    // folded histogram of dst
    for (long long e = (long long)blockIdx.x * 256 + threadIdx.x; e < E;
         e += (long long)gridDim.x * 256)
        atomicAdd(cnt + eidx[(int)e], 1);

    int g = threadIdx.x >> 5;
    int w = threadIdx.x & 31;
    int n = blockIdx.x * 8 + g;

    for (int i = threadIdx.x; i < 1024; i += 256) {
        w1s[i] = W1_s[i];
        w1v[i] = W1_v[i];
    }
    if (n < N) {
        float4 q = *(const float4*)(nf + (size_t)n * 128 + w * 4);
        *(float4*)&nrow[g][w * 4] = q;
    }
    __syncthreads();
    if (n >= N) return;

    const float l1 = 0.17677669529663687f; // 1/sqrt(32)
    const float* r = nrow[g];
    float ss = 0.f, vx = 0.f, vy = 0.f, vz = 0.f;
#pragma unroll 8
    for (int u = 0; u < 32; ++u) {
        float ws = w1s[u * 32 + w];
        float wv = w1v[u * 32 + w];
        ss += r[u] * ws;
        vx += r[32 + u * 3 + 0] * wv;
        vy += r[32 + u * 3 + 1] * wv;
        vz += r[32 + u * 3 + 2] * wv;
    }
    ushort4 o;
    o.x = f2bf(ss * l1); o.y = f2bf(vx * l1);
    o.z = f2bf(vy * l1); o.w = f2bf(vz * l1);
    *(ushort4*)(sv1 + (size_t)n * 128 + w * 4) = o;
}

// ---------------- CSR build ----------------

__global__ __launch_bounds__(1024) void scan_a(
    const int* __restrict__ cnt, int* __restrict__ rs,
    int* __restrict__ bsum, int N)
{
    int i = blockIdx.x * 1024 + threadIdx.x;
    int lane = threadIdx.x & 63;
    int wid = threadIdx.x >> 6;
    int v = (i < N) ? cnt[i] : 0;
    int incl = v;
#pragma unroll
    for (int d = 1; d < 64; d <<= 1) {
        int t = __shfl_up(incl, d);
        if (lane >= d) incl += t;
    }
    __shared__ int wtot[16];
    __shared__ int woff[16];
    if (lane == 63) wtot[wid] = incl;
    __syncthreads();
    if (wid == 0) {
        int t = (lane < 16) ? wtot[lane] : 0;
        int s = t;
#pragma unroll
        for (int d = 1; d < 16; d <<= 1) {
            int q = __shfl_up(s, d);
            if (lane >= d) s += q;
        }
        if (lane < 16) woff[lane] = s - t;
        if (lane == 15) bsum[blockIdx.x] = s;
    }
    __syncthreads();
    if (i < N) rs[i] = woff[wid] + incl - v;
}

__global__ __launch_bounds__(64) void scan_b(
    const int* __restrict__ bsum, int* __restrict__ boff, int nb)
{
    int lane = threadIdx.x;
    int carry = 0;
    for (int base = 0; base < nb; base += 64) {
        int i = base + lane;
        int v = (i < nb) ? bsum[i] : 0;
        int s = v;
#pragma unroll
        for (int d = 1; d < 64; d <<= 1) {
            int t = __shfl_up(s, d);
            if (lane >= d) s += t;
        }
        if (i < nb) boff[i] = carry + s - v;
        carry += __shfl(s, 63);
    }
}

__global__ __launch_bounds__(1024) void scan_c(
    int* __restrict__ rs, const int* __restrict__ boff, int N)
{
    int i = blockIdx.x * 1024 + threadIdx.x;
    if (i < N) rs[i] += boff[blockIdx.x];
}

__global__ __launch_bounds__(256) void scatter_kernel(
    const int* __restrict__ eidx, int* __restrict__ rs,
    int* __restrict__ perm, int E)
{
    int e = blockIdx.x * 256 + threadIdx.x;
    if (e < E) {
        int d = eidx[e];
        int p = atomicAdd(rs + d, 1);
        perm[p] = e;
    }
}

// ---------------- per-node reduction (no atomics) ----------------

__global__ __launch_bounds__(256) void reduce_kernel(
    const float* __restrict__ ea, const float* __restrict__ ee,
    const float* __restrict__ fc1, const float* __restrict__ fc2,
    const ushort* __restrict__ sv1, const int* __restrict__ eidx,
    const int* __restrict__ perm, const int* __restrict__ rs_end,
    const int* __restrict__ cnt, float* __restrict__ SV, int N, int E)
{
    __shared__ float rec[8][13][32]; // k-major: conflict-free writes, bcast reads
    __shared__ float fc1s[64];
    int g = threadIdx.x >> 5;
    int u = threadIdx.x & 31;
    int n = blockIdx.x * 8 + g;

    if (threadIdx.x < 64) fc1s[threadIdx.x] = fc1[threadIdx.x];
    __syncthreads();
    if (n >= N) return;

    const float rs8 = 0.35355339059327373f;      // 1/sqrt(8)
    const float inv_sqrt3 = 0.5773502691896258f;

    float f2r[8][4];
#pragma unroll
    for (int k = 0; k < 8; ++k)
#pragma unroll
        for (int j = 0; j < 4; ++j)
            f2r[k][j] = fc2[k * 128 + j * 32 + u];

    int count = cnt[n];
    int end = rs_end[n];     // after scatter: rs[n] = start + cnt[n]
    int start = end - count;

    float aS0 = 0.f, aS1 = 0.f;
    float aV0x = 0.f, aV0y = 0.f, aV0z = 0.f;
    float aV1x = 0.f, aV1y = 0.f, aV1z = 0.f;

    for (int j0 = 0; j0 < count; j0 += 32) {
        int nk = count - j0; if (nk > 32) nk = 32;
        // phase 1: lane u computes MLP for edge slot u
        if (u < nk) {
            int e = perm[start + j0 + u];
            const float* eep = ee + (size_t)e * 8;
            float4 e0 = *(const float4*)eep;
            float4 e1 = *(const float4*)(eep + 4);
            float ev[8] = {e0.x, e0.y, e0.z, e0.w, e1.x, e1.y, e1.z, e1.w};
#pragma unroll
            for (int k = 0; k < 8; ++k) {
                float t = 0.f;
#pragma unroll
                for (int i = 0; i < 8; ++i) t += ev[i] * fc1s[i * 8 + k];
                t *= rs8;
                rec[g][k][u] = (t / (1.f + expf(-t))) * rs8;
            }
            float4 a4 = *(const float4*)(ea + (size_t)e * 4);
            rec[g][8][u]  = a4.x;
            rec[g][9][u]  = a4.y;
            rec[g][10][u] = a4.z;
            rec[g][11][u] = a4.w;
            rec[g][12][u] = __int_as_float(eidx[E + e]);
        }

        // phase 2: straight-line 2-way unroll, 2 outstanding gathers
        auto edge_body = [&](int jj, ushort4 q) {
            float ss = bf2f(q.x), vx = bf2f(q.y), vy = bf2f(q.z), vz = bf2f(q.w);
            float h0 = rec[g][0][jj], h1 = rec[g][1][jj];
            float h2 = rec[g][2][jj], h3 = rec[g][3][jj];
            float h4 = rec[g][4][jj], h5 = rec[g][5][jj];
            float h6 = rec[g][6][jj], h7 = rec[g][7][jj];
            float b0 = rec[g][8][jj], bx = rec[g][9][jj];
            float by = rec[g][10][jj], bz = rec[g][11][jj];

            float w0 = h0*f2r[0][0] + h1*f2r[1][0] + h2*f2r[2][0] + h3*f2r[3][0]
                     + h4*f2r[4][0] + h5*f2r[5][0] + h6*f2r[6][0] + h7*f2r[7][0];
            float w1 = h0*f2r[0][1] + h1*f2r[1][1] + h2*f2r[2][1] + h3*f2r[3][1]
                     + h4*f2r[4][1] + h5*f2r[5][1] + h6*f2r[6][1] + h7*f2r[7][1];
            float w2 = h0*f2r[0][2] + h1*f2r[1][2] + h2*f2r[2][2] + h3*f2r[3][2]
                     + h4*f2r[4][2] + h5*f2r[5][2] + h6*f2r[6][2] + h7*f2r[7][2];
            float w3 = h0*f2r[0][3] + h1*f2r[1][3] + h2*f2r[2][3] + h3*f2r[3][3]
                     + h4*f2r[4][3] + h5*f2r[5][3] + h6*f2r[6][3] + h7*f2r[7][3];

            float dv = vx * bx + vy * by + vz * bz;
            aS0 += w0 * ss * b0;
            aS1 += w3 * dv;
            float c1 = w1 * ss;
            aV0x += c1 * bx; aV0y += c1 * by; aV0z += c1 * bz;
            float c2 = w2 * b0;
            aV1x += c2 * vx; aV1y += c2 * vy; aV1z += c2 * vz;
        };

        int nkp = nk & ~1;
        for (int jj = 0; jj < nkp; jj += 2) {
            int sA = __float_as_int(rec[g][12][jj]);
            int sB = __float_as_int(rec[g][12][jj + 1]);
            ushort4 qA = *(const ushort4*)(sv1 + (size_t)sA * 128 + u * 4);
            ushort4 qB = *(const ushort4*)(sv1 + (size_t)sB * 128 + u * 4);
            edge_body(jj, qA);
            edge_body(jj + 1, qB);
        }
        if (nk & 1) {
            int sA = __float_as_int(rec[g][12][nk - 1]);
            ushort4 qA = *(const ushort4*)(sv1 + (size_t)sA * 128 + u * 4);
            edge_body(nk - 1, qA);
        }
    }

    // packed SV[n][u][8] = {S0, S1*inv_sqrt3, V0x,V0y,V0z, V1x,V1y,V1z}
    float* o = SV + (size_t)n * 256 + u * 8;
    *(float4*)o       = make_float4(aS0, aS1 * inv_sqrt3, aV0x, aV0y);
    *(float4*)(o + 4) = make_float4(aV0z, aV1x, aV1y, aV1z);
}

// ---------------- fallback (atomic path, packed layouts) ----------------

__global__ __launch_bounds__(256) void edge_kernel(
    const float* __restrict__ ea, const float* __restrict__ ee,
    const float* __restrict__ fc1, const float* __restrict__ fc2,
    const ushort* __restrict__ sv1, const int* __restrict__ eidx,
    float* __restrict__ SV, int E)
{
    long long tid = (long long)blockIdx.x * 256 + threadIdx.x;
    int e = (int)(tid >> 5);
    int u = (int)(tid & 31);
    if (e >= E) return;
    const float rs8 = 0.35355339059327373f;
    const float inv_sqrt3 = 0.5773502691896258f;
    float ev[8];
#pragma unroll
    for (int i = 0; i < 8; ++i) ev[i] = ee[(size_t)e * 8 + i];
    float h[8];
#pragma unroll
    for (int k = 0; k < 8; ++k) {
        float t = 0.f;
#pragma unroll
        for (int i = 0; i < 8; ++i) t += ev[i] * fc1[i * 8 + k];
        t *= rs8;
        h[k] = t / (1.f + expf(-t));
    }
    float w0 = 0.f, w1 = 0.f, w2 = 0.f, w3 = 0.f;
#pragma unroll
    for (int k = 0; k < 8; ++k) {
        const float* f2 = fc2 + k * 128;
        float hk = h[k];
        w0 += hk * f2[u];
        w1 += hk * f2[32 + u];
        w2 += hk * f2[64 + u];
        w3 += hk * f2[96 + u];
    }
    w0 *= rs8; w1 *= rs8; w2 *= rs8; w3 *= rs8;
    int dst = eidx[e];
    int src = eidx[E + e];
    float a0 = ea[(size_t)e * 4 + 0];
    float ax = ea[(size_t)e * 4 + 1];
    float ay = ea[(size_t)e * 4 + 2];
    float az = ea[(size_t)e * 4 + 3];
    ushort4 q = *(const ushort4*)(sv1 + (size_t)src * 128 + u * 4);
    float ss = bf2f(q.x), vx = bf2f(q.y), vy = bf2f(q.z), vz = bf2f(q.w);
    float dv = vx * ax + vy * ay + vz * az;
    float* o = SV + (size_t)dst * 256 + u * 8;
    atomicAdd(o + 0, w0 * ss * a0);
    atomicAdd(o + 1, w3 * dv * inv_sqrt3);
    float c1 = w1 * ss;
    atomicAdd(o + 2, c1 * ax);
    atomicAdd(o + 3, c1 * ay);
    atomicAdd(o + 4, c1 * az);
    float c2 = w2 * a0;
    atomicAdd(o + 5, c2 * vx);
    atomicAdd(o + 6, c2 * vy);
    atomicAdd(o + 7, c2 * vz);
}

// ---------------- final linear + skip (block-staged packed weights) -------

__global__ __launch_bounds__(256) void node_final(
    const float* __restrict__ SV, const float* __restrict__ W2_s,
    const float* __restrict__ W2_v, const float* __restrict__ nf,
    const float* __restrict__ nattr, const float* __restrict__ Wsc_s,
    const float* __restrict__ Wsc_v, float* __restrict__ out, int N)
{
    __shared__ float wq[4096];   // {w2s[u][w], w2s[u+32][w], w2v[u][w], w2v[u+32][w]}
    __shared__ float wsp[4096];  // {Wsc_s[u][a][w]}a=0..3
    __shared__ float wvp[4096];
    __shared__ float svt[8][8][32];
    __shared__ float nrow[8][128];

    int g = threadIdx.x >> 5;
    int w = threadIdx.x & 31;

    for (int i = threadIdx.x; i < 1024; i += 256) {  // i = u*32+w
        int uu = i >> 5, ww = i & 31;
        *(float4*)&wq[i * 4] = make_float4(W2_s[i], W2_s[i + 1024],
                                           W2_v[i], W2_v[i + 1024]);
        const float* ps = Wsc_s + (size_t)uu * 128 + ww;
        const float* pv = Wsc_v + (size_t)uu * 128 + ww;
        *(float4*)&wsp[i * 4] = make_float4(ps[0], ps[32], ps[64], ps[96]);
        *(float4*)&wvp[i * 4] = make_float4(pv[0], pv[32], pv[64], pv[96]);
    }
    __syncthreads();

    const float l2 = 0.125f;                    // 1/sqrt(64)
    const float sc_norm = 0.08838834764831843f; // 1/sqrt(128)

    for (int t = 0; t < 4; ++t) {
        int n = blockIdx.x * 32 + g * 4 + t;
        if (n >= N) continue;
        const float* svp = SV + (size_t)n * 256 + w * 8;
        float4 p0 = *(const float4*)svp;
        float4 p1 = *(const float4*)(svp + 4);
        svt[g][0][w] = p0.x; svt[g][1][w] = p0.y;
        svt[g][2][w] = p0.z; svt[g][3][w] = p0.w;
        svt[g][4][w] = p1.x; svt[g][5][w] = p1.y;
        svt[g][6][w] = p1.z; svt[g][7][w] = p1.w;
        float4 q = *(const float4*)(nf + (size_t)n * 128 + w * 4);
        *(float4*)&nrow[g][w * 4] = q;
        float at0 = nattr[(size_t)n * 4 + 0];
        float at1 = nattr[(size_t)n * 4 + 1];
        float at2 = nattr[(size_t)n * 4 + 2];
        float at3 = nattr[(size_t)n * 4 + 3];

        float sa = 0.f, va0 = 0.f, va1 = 0.f, va2 = 0.f;
        float scs = 0.f, scv0 = 0.f, scv1 = 0.f, scv2 = 0.f;
#pragma unroll
        for (int u = 0; u < 32; ++u) {
            float4 qw = *(const float4*)&wq[(u * 32 + w) * 4];
            sa  += svt[g][0][u] * qw.x + svt[g][1][u] * qw.y;
            va0 += svt[g][2][u] * qw.z + svt[g][5][u] * qw.w;
            va1 += svt[g][3][u] * qw.z + svt[g][6][u] * qw.w;
            va2 += svt[g][4][u] * qw.z + svt[g][7][u] * qw.w;
            float4 ps = *(const float4*)&wsp[(u * 32 + w) * 4];
            float4 pv = *(const float4*)&wvp[(u * 32 + w) * 4];
            float cs = at0 * ps.x + at1 * ps.y + at2 * ps.z + at3 * ps.w;
            float cv = at0 * pv.x + at1 * pv.y + at2 * pv.z + at3 * pv.w;
            scs  += nrow[g][u] * cs;
            scv0 += nrow[g][32 + u * 3 + 0] * cv;
            scv1 += nrow[g][32 + u * 3 + 1] * cv;
            scv2 += nrow[g][32 + u * 3 + 2] * cv;
        }
        float* orow = out + (size_t)n * 128;
        orow[w] = sa * l2 + scs * sc_norm;
        orow[32 + w * 3 + 0] = va0 * l2 + scv0 * sc_norm;
        orow[32 + w * 3 + 1] = va1 * l2 + scv1 * sc_norm;
        orow[32 + w * 3 + 2] = va2 * l2 + scv2 * sc_norm;
    }
}

extern "C" void kernel_launch(void* const* d_in, const int* in_sizes, int n_in,
                              void* d_out, int out_size, void* d_ws, size_t ws_size,
                              hipStream_t stream) {
    const float* nf    = (const float*)d_in[0];
    const float* nattr = (const float*)d_in[1];
    const float* ea    = (const float*)d_in[2];
    const float* ee    = (const float*)d_in[3];
    const float* W1_s  = (const float*)d_in[4];
    const float* W1_v  = (const float*)d_in[5];
    const float* fc1   = (const float*)d_in[6];
    const float* fc2   = (const float*)d_in[7];
    const float* W2_s  = (const float*)d_in[8];
    const float* W2_v  = (const float*)d_in[9];
    const float* Wsc_s = (const float*)d_in[10];
    const float* Wsc_v = (const float*)d_in[11];
    const int*   eidx  = (const int*)d_in[12];

    int N = in_sizes[0] / 128;
    int E = in_sizes[12] / 2;

    float* ws = (float*)d_ws;
    ushort* sv1 = (ushort*)ws;                  // N*128 ushorts (= N*64 floats)
    float* SV  = ws + (size_t)N * 64;           // N*256
    int* cnt  = (int*)(SV + (size_t)N * 256);   // N
    int* rs   = cnt + N;                        // N
    int* bsum = rs + N;                         // 64
    int* boff = bsum + 64;                      // 64
    int* perm = boff + 64;                      // E

    size_t needed = ((size_t)N * 320 + 2 * (size_t)N + 128 + (size_t)E) * 4;

    int nb_node = (N + 7) / 8;
    int nbE = (E + 255) / 256;
    int nb_final = (N + 31) / 32;

    if (ws_size >= needed) {
        hipMemsetAsync(cnt, 0, (size_t)N * sizeof(int), stream);
        node_prep<<<nb_node, 256, 0, stream>>>(nf, W1_s, W1_v, eidx, cnt, sv1, N, E);
        int nbS = (N + 1023) / 1024;
        scan_a<<<nbS, 1024, 0, stream>>>(cnt, rs, bsum, N);
        scan_b<<<1, 64, 0, stream>>>(bsum, boff, nbS);
        scan_c<<<nbS, 1024, 0, stream>>>(rs, boff, N);
        scatter_kernel<<<nbE, 256, 0, stream>>>(eidx, rs, perm, E);
        reduce_kernel<<<nb_node, 256, 0, stream>>>(ea, ee, fc1, fc2, sv1, eidx,
                                                   perm, rs, cnt, SV, N, E);
        node_final<<<nb_final, 256, 0, stream>>>(SV, W2_s, W2_v, nf, nattr,
                                                 Wsc_s, Wsc_v, (float*)d_out, N);
    } else {
        hipMemsetAsync(SV, 0, (size_t)N * 256 * sizeof(float), stream);
        node_prep<<<nb_node, 256, 0, stream>>>(nf, W1_s, W1_v, eidx, cnt, sv1, N, E);
        long long tot = (long long)E * 32;
        int nb_edge = (int)((tot + 255) / 256);
        edge_kernel<<<nb_edge, 256, 0, stream>>>(ea, ee, fc1, fc2, sv1, eidx, SV, E);
        node_final<<<nb_final, 256, 0, stream>>>(SV, W2_s, W2_v, nf, nattr,
                                                 Wsc_s, Wsc_v, (float*)d_out, N);
    }
}

// Round 6
// 262.598 us; speedup vs baseline: 1.1434x; 1.1434x over previous
//
#include <hip/hip_runtime.h>
#include <math.h>

// ---------------------------------------------------------------------------
// InteractionBlock: gather -> per-edge tensor-product -> scatter -> linear
// N=50000 nodes, E=800000 edges, MUL=32.
//
// Round-6 (reduce_kernel only):
//  * wave64 per node: lanes = (edge-parity h, channel u). Kills intra-wave
//    divergence between the two 32-lane groups (they were on different
//    nodes). Final combine: 8x __shfl_xor(acc, 32).
//  * rec slot-major [64][20] (80 B stride): phase-2 record read = 3x
//    ds_read_b128 + 1x b32 (uniform/broadcast) instead of 13x b32; 80 B
//    stride bank-balances the phase-1 b128 writes (20s mod 32 spreads).
//  * __expf + rcp silu (v_exp, not libm), branch-free masked tail.
//  * simple loop: no unroll, no prefetch (R4/R5 post-mortem: those ADDED
//    issue slots; VALU-busy-time rose 48->57->62 us).
//
// ws layout (4B units):
//   sv1[N*64 (as ushort N*128)] | SV[N*256] | cnt[N] | rs[N] |
//   bsum[64] | boff[64] | perm[E]        (~67.6 MB)
// ---------------------------------------------------------------------------

__device__ __forceinline__ unsigned short f2bf(float x) {
    unsigned u = __float_as_uint(x);
    u += 0x7FFFu + ((u >> 16) & 1u);   // RNE
    return (unsigned short)(u >> 16);
}
__device__ __forceinline__ float bf2f(unsigned short h) {
    return __uint_as_float(((unsigned)h) << 16);
}

__global__ __launch_bounds__(256) void node_prep(
    const float* __restrict__ nf, const float* __restrict__ W1_s,
    const float* __restrict__ W1_v, const int* __restrict__ eidx,
    int* __restrict__ cnt, ushort* __restrict__ sv1, int N, int E)
{
    __shared__ float w1s[1024];
    __shared__ float w1v[1024];
    __shared__ float nrow[8][128];

    // folded histogram of dst
    for (long long e = (long long)blockIdx.x * 256 + threadIdx.x; e < E;
         e += (long long)gridDim.x * 256)
        atomicAdd(cnt + eidx[(int)e], 1);

    int g = threadIdx.x >> 5;
    int w = threadIdx.x & 31;
    int n = blockIdx.x * 8 + g;

    for (int i = threadIdx.x; i < 1024; i += 256) {
        w1s[i] = W1_s[i];
        w1v[i] = W1_v[i];
    }
    if (n < N) {
        float4 q = *(const float4*)(nf + (size_t)n * 128 + w * 4);
        *(float4*)&nrow[g][w * 4] = q;
    }
    __syncthreads();
    if (n >= N) return;

    const float l1 = 0.17677669529663687f; // 1/sqrt(32)
    const float* r = nrow[g];
    float ss = 0.f, vx = 0.f, vy = 0.f, vz = 0.f;
#pragma unroll 8
    for (int u = 0; u < 32; ++u) {
        float ws = w1s[u * 32 + w];
        float wv = w1v[u * 32 + w];
        ss += r[u] * ws;
        vx += r[32 + u * 3 + 0] * wv;
        vy += r[32 + u * 3 + 1] * wv;
        vz += r[32 + u * 3 + 2] * wv;
    }
    ushort4 o;
    o.x = f2bf(ss * l1); o.y = f2bf(vx * l1);
    o.z = f2bf(vy * l1); o.w = f2bf(vz * l1);
    *(ushort4*)(sv1 + (size_t)n * 128 + w * 4) = o;
}

// ---------------- CSR build ----------------

__global__ __launch_bounds__(1024) void scan_a(
    const int* __restrict__ cnt, int* __restrict__ rs,
    int* __restrict__ bsum, int N)
{
    int i = blockIdx.x * 1024 + threadIdx.x;
    int lane = threadIdx.x & 63;
    int wid = threadIdx.x >> 6;
    int v = (i < N) ? cnt[i] : 0;
    int incl = v;
#pragma unroll
    for (int d = 1; d < 64; d <<= 1) {
        int t = __shfl_up(incl, d);
        if (lane >= d) incl += t;
    }
    __shared__ int wtot[16];
    __shared__ int woff[16];
    if (lane == 63) wtot[wid] = incl;
    __syncthreads();
    if (wid == 0) {
        int t = (lane < 16) ? wtot[lane] : 0;
        int s = t;
#pragma unroll
        for (int d = 1; d < 16; d <<= 1) {
            int q = __shfl_up(s, d);
            if (lane >= d) s += q;
        }
        if (lane < 16) woff[lane] = s - t;
        if (lane == 15) bsum[blockIdx.x] = s;
    }
    __syncthreads();
    if (i < N) rs[i] = woff[wid] + incl - v;
}

__global__ __launch_bounds__(64) void scan_b(
    const int* __restrict__ bsum, int* __restrict__ boff, int nb)
{
    int lane = threadIdx.x;
    int carry = 0;
    for (int base = 0; base < nb; base += 64) {
        int i = base + lane;
        int v = (i < nb) ? bsum[i] : 0;
        int s = v;
#pragma unroll
        for (int d = 1; d < 64; d <<= 1) {
            int t = __shfl_up(s, d);
            if (lane >= d) s += t;
        }
        if (i < nb) boff[i] = carry + s - v;
        carry += __shfl(s, 63);
    }
}

__global__ __launch_bounds__(1024) void scan_c(
    int* __restrict__ rs, const int* __restrict__ boff, int N)
{
    int i = blockIdx.x * 1024 + threadIdx.x;
    if (i < N) rs[i] += boff[blockIdx.x];
}

__global__ __launch_bounds__(256) void scatter_kernel(
    const int* __restrict__ eidx, int* __restrict__ rs,
    int* __restrict__ perm, int E)
{
    int e = blockIdx.x * 256 + threadIdx.x;
    if (e < E) {
        int d = eidx[e];
        int p = atomicAdd(rs + d, 1);
        perm[p] = e;
    }
}

// ---------------- per-node reduction (no atomics, wave64/node) ------------

__global__ __launch_bounds__(256) void reduce_kernel(
    const float* __restrict__ ea, const float* __restrict__ ee,
    const float* __restrict__ fc1, const float* __restrict__ fc2,
    const ushort* __restrict__ sv1, const int* __restrict__ eidx,
    const int* __restrict__ perm, const int* __restrict__ rs_end,
    const int* __restrict__ cnt, float* __restrict__ SV, int N, int E)
{
    // slot-major, 20-float (80 B) stride: bank-balanced b128 writes,
    // uniform (broadcast) b128 reads.
    __shared__ float rec[4][64][20];   // 20.5 KB

    int wid = threadIdx.x >> 6;
    int l   = threadIdx.x & 63;
    int h   = l >> 5;
    int u   = l & 31;
    int n = blockIdx.x * 4 + wid;
    if (n >= N) return;

    const float rs8 = 0.35355339059327373f;      // 1/sqrt(8)
    const float inv_sqrt3 = 0.5773502691896258f;

    float f2r[8][4];
#pragma unroll
    for (int k = 0; k < 8; ++k)
#pragma unroll
        for (int j = 0; j < 4; ++j)
            f2r[k][j] = fc2[k * 128 + j * 32 + u];

    int count = cnt[n];
    int start = rs_end[n] - count;

    float aS0 = 0.f, aS1 = 0.f;
    float aV0x = 0.f, aV0y = 0.f, aV0z = 0.f;
    float aV1x = 0.f, aV1y = 0.f, aV1z = 0.f;

    for (int j0 = 0; j0 < count; j0 += 64) {
        int nk = count - j0; if (nk > 64) nk = 64;
        // phase 1: lane l computes the edge MLP for slot l (same wave, no
        // barrier needed)
        if (l < nk) {
            int e = perm[start + j0 + l];
            const float* eep = ee + (size_t)e * 8;
            float4 e0 = *(const float4*)eep;
            float4 e1 = *(const float4*)(eep + 4);
            float ev[8] = {e0.x, e0.y, e0.z, e0.w, e1.x, e1.y, e1.z, e1.w};
            float hh[8];
#pragma unroll
            for (int k = 0; k < 8; ++k) {
                float t = 0.f;
#pragma unroll
                for (int i = 0; i < 8; ++i) t += ev[i] * fc1[i * 8 + k];
                t *= rs8;
                // fast silu: t * 1/(1+e^-t), folded extra rs8
                hh[k] = t * __builtin_amdgcn_rcpf(1.f + __expf(-t)) * rs8;
            }
            float* rr = &rec[wid][l][0];
            *(float4*)rr       = make_float4(hh[0], hh[1], hh[2], hh[3]);
            *(float4*)(rr + 4) = make_float4(hh[4], hh[5], hh[6], hh[7]);
            *(float4*)(rr + 8) = *(const float4*)(ea + (size_t)e * 4);
            rr[12] = __int_as_float(eidx[E + e]);
        }
        // phase 2: the wave processes 2 edges/iteration (h picks the edge)
        int pairs = (nk + 1) >> 1;
        for (int jj = 0; jj < pairs; ++jj) {
            int slot = jj * 2 + h;
            float msk = (slot < nk) ? 1.f : 0.f;
            int slotc = slot < nk ? slot : nk - 1;
            const float* rr = &rec[wid][slotc][0];
            float4 H0 = *(const float4*)rr;        // h0..h3 (x rs8^2)
            float4 H1 = *(const float4*)(rr + 4);  // h4..h7
            float4 A  = *(const float4*)(rr + 8);  // a0, ax, ay, az
            int src = __float_as_int(rr[12]);
            ushort4 q = *(const ushort4*)(sv1 + (size_t)src * 128 + u * 4);
            float ss = bf2f(q.x) * msk;
            float vx = bf2f(q.y), vy = bf2f(q.z), vz = bf2f(q.w);

            float w0 = H0.x*f2r[0][0] + H0.y*f2r[1][0] + H0.z*f2r[2][0] + H0.w*f2r[3][0]
                     + H1.x*f2r[4][0] + H1.y*f2r[5][0] + H1.z*f2r[6][0] + H1.w*f2r[7][0];
            float w1 = H0.x*f2r[0][1] + H0.y*f2r[1][1] + H0.z*f2r[2][1] + H0.w*f2r[3][1]
                     + H1.x*f2r[4][1] + H1.y*f2r[5][1] + H1.z*f2r[6][1] + H1.w*f2r[7][1];
            float w2 = H0.x*f2r[0][2] + H0.y*f2r[1][2] + H0.z*f2r[2][2] + H0.w*f2r[3][2]
                     + H1.x*f2r[4][2] + H1.y*f2r[5][2] + H1.z*f2r[6][2] + H1.w*f2r[7][2];
            float w3 = H0.x*f2r[0][3] + H0.y*f2r[1][3] + H0.z*f2r[2][3] + H0.w*f2r[3][3]
                     + H1.x*f2r[4][3] + H1.y*f2r[5][3] + H1.z*f2r[6][3] + H1.w*f2r[7][3];

            float dv = (vx * A.y + vy * A.z + vz * A.w) * msk;
            float ssb0 = ss * A.x;
            aS0 += w0 * ssb0;
            aS1 += w3 * dv;
            float c1 = w1 * ss;
            aV0x += c1 * A.y; aV0y += c1 * A.z; aV0z += c1 * A.w;
            float c2 = w2 * A.x * msk;
            aV1x += c2 * vx; aV1y += c2 * vy; aV1z += c2 * vz;
        }
    }

    // combine the two edge-parity halves (lane xor 32)
    aS0  += __shfl_xor(aS0, 32);
    aS1  += __shfl_xor(aS1, 32);
    aV0x += __shfl_xor(aV0x, 32);
    aV0y += __shfl_xor(aV0y, 32);
    aV0z += __shfl_xor(aV0z, 32);
    aV1x += __shfl_xor(aV1x, 32);
    aV1y += __shfl_xor(aV1y, 32);
    aV1z += __shfl_xor(aV1z, 32);

    if (h == 0) {
        // packed SV[n][u][8] = {S0, S1*inv_sqrt3, V0x,V0y,V0z, V1x,V1y,V1z}
        float* o = SV + (size_t)n * 256 + u * 8;
        *(float4*)o       = make_float4(aS0, aS1 * inv_sqrt3, aV0x, aV0y);
        *(float4*)(o + 4) = make_float4(aV0z, aV1x, aV1y, aV1z);
    }
}

// ---------------- fallback (atomic path, packed layouts) ----------------

__global__ __launch_bounds__(256) void edge_kernel(
    const float* __restrict__ ea, const float* __restrict__ ee,
    const float* __restrict__ fc1, const float* __restrict__ fc2,
    const ushort* __restrict__ sv1, const int* __restrict__ eidx,
    float* __restrict__ SV, int E)
{
    long long tid = (long long)blockIdx.x * 256 + threadIdx.x;
    int e = (int)(tid >> 5);
    int u = (int)(tid & 31);
    if (e >= E) return;
    const float rs8 = 0.35355339059327373f;
    const float inv_sqrt3 = 0.5773502691896258f;
    float ev[8];
#pragma unroll
    for (int i = 0; i < 8; ++i) ev[i] = ee[(size_t)e * 8 + i];
    float h[8];
#pragma unroll
    for (int k = 0; k < 8; ++k) {
        float t = 0.f;
#pragma unroll
        for (int i = 0; i < 8; ++i) t += ev[i] * fc1[i * 8 + k];
        t *= rs8;
        h[k] = t / (1.f + expf(-t));
    }
    float w0 = 0.f, w1 = 0.f, w2 = 0.f, w3 = 0.f;
#pragma unroll
    for (int k = 0; k < 8; ++k) {
        const float* f2 = fc2 + k * 128;
        float hk = h[k];
        w0 += hk * f2[u];
        w1 += hk * f2[32 + u];
        w2 += hk * f2[64 + u];
        w3 += hk * f2[96 + u];
    }
    w0 *= rs8; w1 *= rs8; w2 *= rs8; w3 *= rs8;
    int dst = eidx[e];
    int src = eidx[E + e];
    float a0 = ea[(size_t)e * 4 + 0];
    float ax = ea[(size_t)e * 4 + 1];
    float ay = ea[(size_t)e * 4 + 2];
    float az = ea[(size_t)e * 4 + 3];
    ushort4 q = *(const ushort4*)(sv1 + (size_t)src * 128 + u * 4);
    float ss = bf2f(q.x), vx = bf2f(q.y), vy = bf2f(q.z), vz = bf2f(q.w);
    float dv = vx * ax + vy * ay + vz * az;
    float* o = SV + (size_t)dst * 256 + u * 8;
    atomicAdd(o + 0, w0 * ss * a0);
    atomicAdd(o + 1, w3 * dv * inv_sqrt3);
    float c1 = w1 * ss;
    atomicAdd(o + 2, c1 * ax);
    atomicAdd(o + 3, c1 * ay);
    atomicAdd(o + 4, c1 * az);
    float c2 = w2 * a0;
    atomicAdd(o + 5, c2 * vx);
    atomicAdd(o + 6, c2 * vy);
    atomicAdd(o + 7, c2 * vz);
}

// ---------------- final linear + skip (block-staged packed weights) -------

__global__ __launch_bounds__(256) void node_final(
    const float* __restrict__ SV, const float* __restrict__ W2_s,
    const float* __restrict__ W2_v, const float* __restrict__ nf,
    const float* __restrict__ nattr, const float* __restrict__ Wsc_s,
    const float* __restrict__ Wsc_v, float* __restrict__ out, int N)
{
    __shared__ float wq[4096];   // {w2s[u][w], w2s[u+32][w], w2v[u][w], w2v[u+32][w]}
    __shared__ float wsp[4096];  // {Wsc_s[u][a][w]}a=0..3
    __shared__ float wvp[4096];
    __shared__ float svt[8][8][32];
    __shared__ float nrow[8][128];

    int g = threadIdx.x >> 5;
    int w = threadIdx.x & 31;

    for (int i = threadIdx.x; i < 1024; i += 256) {  // i = u*32+w
        int uu = i >> 5, ww = i & 31;
        *(float4*)&wq[i * 4] = make_float4(W2_s[i], W2_s[i + 1024],
                                           W2_v[i], W2_v[i + 1024]);
        const float* ps = Wsc_s + (size_t)uu * 128 + ww;
        const float* pv = Wsc_v + (size_t)uu * 128 + ww;
        *(float4*)&wsp[i * 4] = make_float4(ps[0], ps[32], ps[64], ps[96]);
        *(float4*)&wvp[i * 4] = make_float4(pv[0], pv[32], pv[64], pv[96]);
    }
    __syncthreads();

    const float l2 = 0.125f;                    // 1/sqrt(64)
    const float sc_norm = 0.08838834764831843f; // 1/sqrt(128)

    for (int t = 0; t < 4; ++t) {
        int n = blockIdx.x * 32 + g * 4 + t;
        if (n >= N) continue;
        const float* svp = SV + (size_t)n * 256 + w * 8;
        float4 p0 = *(const float4*)svp;
        float4 p1 = *(const float4*)(svp + 4);
        svt[g][0][w] = p0.x; svt[g][1][w] = p0.y;
        svt[g][2][w] = p0.z; svt[g][3][w] = p0.w;
        svt[g][4][w] = p1.x; svt[g][5][w] = p1.y;
        svt[g][6][w] = p1.z; svt[g][7][w] = p1.w;
        float4 q = *(const float4*)(nf + (size_t)n * 128 + w * 4);
        *(float4*)&nrow[g][w * 4] = q;
        float at0 = nattr[(size_t)n * 4 + 0];
        float at1 = nattr[(size_t)n * 4 + 1];
        float at2 = nattr[(size_t)n * 4 + 2];
        float at3 = nattr[(size_t)n * 4 + 3];

        float sa = 0.f, va0 = 0.f, va1 = 0.f, va2 = 0.f;
        float scs = 0.f, scv0 = 0.f, scv1 = 0.f, scv2 = 0.f;
#pragma unroll
        for (int u = 0; u < 32; ++u) {
            float4 qw = *(const float4*)&wq[(u * 32 + w) * 4];
            sa  += svt[g][0][u] * qw.x + svt[g][1][u] * qw.y;
            va0 += svt[g][2][u] * qw.z + svt[g][5][u] * qw.w;
            va1 += svt[g][3][u] * qw.z + svt[g][6][u] * qw.w;
            va2 += svt[g][4][u] * qw.z + svt[g][7][u] * qw.w;
            float4 ps = *(const float4*)&wsp[(u * 32 + w) * 4];
            float4 pv = *(const float4*)&wvp[(u * 32 + w) * 4];
            float cs = at0 * ps.x + at1 * ps.y + at2 * ps.z + at3 * ps.w;
            float cv = at0 * pv.x + at1 * pv.y + at2 * pv.z + at3 * pv.w;
            scs  += nrow[g][u] * cs;
            scv0 += nrow[g][32 + u * 3 + 0] * cv;
            scv1 += nrow[g][32 + u * 3 + 1] * cv;
            scv2 += nrow[g][32 + u * 3 + 2] * cv;
        }
        float* orow = out + (size_t)n * 128;
        orow[w] = sa * l2 + scs * sc_norm;
        orow[32 + w * 3 + 0] = va0 * l2 + scv0 * sc_norm;
        orow[32 + w * 3 + 1] = va1 * l2 + scv1 * sc_norm;
        orow[32 + w * 3 + 2] = va2 * l2 + scv2 * sc_norm;
    }
}

extern "C" void kernel_launch(void* const* d_in, const int* in_sizes, int n_in,
                              void* d_out, int out_size, void* d_ws, size_t ws_size,
                              hipStream_t stream) {
    const float* nf    = (const float*)d_in[0];
    const float* nattr = (const float*)d_in[1];
    const float* ea    = (const float*)d_in[2];
    const float* ee    = (const float*)d_in[3];
    const float* W1_s  = (const float*)d_in[4];
    const float* W1_v  = (const float*)d_in[5];
    const float* fc1   = (const float*)d_in[6];
    const float* fc2   = (const float*)d_in[7];
    const float* W2_s  = (const float*)d_in[8];
    const float* W2_v  = (const float*)d_in[9];
    const float* Wsc_s = (const float*)d_in[10];
    const float* Wsc_v = (const float*)d_in[11];
    const int*   eidx  = (const int*)d_in[12];

    int N = in_sizes[0] / 128;
    int E = in_sizes[12] / 2;

    float* ws = (float*)d_ws;
    ushort* sv1 = (ushort*)ws;                  // N*128 ushorts (= N*64 floats)
    float* SV  = ws + (size_t)N * 64;           // N*256
    int* cnt  = (int*)(SV + (size_t)N * 256);   // N
    int* rs   = cnt + N;                        // N
    int* bsum = rs + N;                         // 64
    int* boff = bsum + 64;                      // 64
    int* perm = boff + 64;                      // E

    size_t needed = ((size_t)N * 320 + 2 * (size_t)N + 128 + (size_t)E) * 4;

    int nb_node = (N + 7) / 8;
    int nbE = (E + 255) / 256;
    int nb_final = (N + 31) / 32;

    if (ws_size >= needed) {
        hipMemsetAsync(cnt, 0, (size_t)N * sizeof(int), stream);
        node_prep<<<nb_node, 256, 0, stream>>>(nf, W1_s, W1_v, eidx, cnt, sv1, N, E);
        int nbS = (N + 1023) / 1024;
        scan_a<<<nbS, 1024, 0, stream>>>(cnt, rs, bsum, N);
        scan_b<<<1, 64, 0, stream>>>(bsum, boff, nbS);
        scan_c<<<nbS, 1024, 0, stream>>>(rs, boff, N);
        scatter_kernel<<<nbE, 256, 0, stream>>>(eidx, rs, perm, E);
        int nb_red = (N + 3) / 4;
        reduce_kernel<<<nb_red, 256, 0, stream>>>(ea, ee, fc1, fc2, sv1, eidx,
                                                  perm, rs, cnt, SV, N, E);
        node_final<<<nb_final, 256, 0, stream>>>(SV, W2_s, W2_v, nf, nattr,
                                                 Wsc_s, Wsc_v, (float*)d_out, N);
    } else {
        hipMemsetAsync(SV, 0, (size_t)N * 256 * sizeof(float), stream);
        node_prep<<<nb_node, 256, 0, stream>>>(nf, W1_s, W1_v, eidx, cnt, sv1, N, E);
        long long tot = (long long)E * 32;
        int nb_edge = (int)((tot + 255) / 256);
        edge_kernel<<<nb_edge, 256, 0, stream>>>(ea, ee, fc1, fc2, sv1, eidx, SV, E);
        node_final<<<nb_final, 256, 0, stream>>>(SV, W2_s, W2_v, nf, nattr,
                                                 Wsc_s, Wsc_v, (float*)d_out, N);
    }
}